// Round 1
// baseline (2363.227 us; speedup 1.0000x reference)
//
#include <hip/hip_runtime.h>
#include <math.h>

#define N_NODES 102400
#define N_EDGES 1638400
#define E_TOT   (N_EDGES + N_NODES)   // 1740800
#define G_GRAPHS 256
#define F_IN  64
#define H1    4
#define C1    32
#define F_MID 128                      // H1*C1
#define C2    32
#define CLIN  5
#define NEG   0.2f

// ---- order-preserving float<->uint encoding for atomicMax ----
__device__ __forceinline__ unsigned enc_f(float f) {
    unsigned b = __float_as_uint(f);
    return (b & 0x80000000u) ? ~b : (b | 0x80000000u);
}
__device__ __forceinline__ float dec_f(unsigned u) {
    unsigned b = (u & 0x80000000u) ? (u & 0x7fffffffu) : ~u;
    return __uint_as_float(b);
}

__device__ __forceinline__ float lrelu(float x) { return x > 0.f ? x : NEG * x; }
__device__ __forceinline__ float elu(float x)   { return x > 0.f ? x : expm1f(x); }

// ---- layer 1 GEMM: h1 = x @ W1  (N x 64 @ 64 x 128), plus attention logits ----
__global__ __launch_bounds__(128) void gemm1(
    const float* __restrict__ x, const float* __restrict__ W1,
    const float* __restrict__ a_src, const float* __restrict__ a_dst,
    float* __restrict__ h1, float* __restrict__ al_src, float* __restrict__ al_dst)
{
    int n = blockIdx.x;
    int t = threadIdx.x;               // 0..127
    __shared__ float xs[F_IN];
    __shared__ float hs[F_MID];
    if (t < F_IN) xs[t] = x[(size_t)n * F_IN + t];
    __syncthreads();
    float acc = 0.f;
#pragma unroll
    for (int k = 0; k < F_IN; ++k) acc += xs[k] * W1[k * F_MID + t];
    h1[(size_t)n * F_MID + t] = acc;
    hs[t] = acc;
    __syncthreads();
    if (t < 8) {
        int h = t & 3;
        const float* a = (t < 4) ? a_src : a_dst;
        float s = 0.f;
#pragma unroll
        for (int c = 0; c < C1; ++c) s += hs[h * C1 + c] * a[h * C1 + c];
        if (t < 4) al_src[n * H1 + h] = s;
        else       al_dst[n * H1 + h] = s;
    }
}

// ---- edge softmax pass 1: per-dst max ----
__global__ __launch_bounds__(256) void edge_max1(
    const int* __restrict__ ei, const float* __restrict__ al_src,
    const float* __restrict__ al_dst, unsigned* __restrict__ m1)
{
    int i = blockIdx.x * 256 + threadIdx.x;
    if (i >= E_TOT) return;
    int s, d;
    if (i < N_EDGES) { s = ei[i]; d = ei[N_EDGES + i]; } else { s = d = i - N_EDGES; }
#pragma unroll
    for (int h = 0; h < H1; ++h) {
        float e = lrelu(al_src[s * H1 + h] + al_dst[d * H1 + h]);
        atomicMax(&m1[d * H1 + h], enc_f(e));
    }
}

// ---- edge softmax pass 2: denominator ----
__global__ __launch_bounds__(256) void edge_den1(
    const int* __restrict__ ei, const float* __restrict__ al_src,
    const float* __restrict__ al_dst, const unsigned* __restrict__ m1,
    float* __restrict__ den1)
{
    int i = blockIdx.x * 256 + threadIdx.x;
    if (i >= E_TOT) return;
    int s, d;
    if (i < N_EDGES) { s = ei[i]; d = ei[N_EDGES + i]; } else { s = d = i - N_EDGES; }
#pragma unroll
    for (int h = 0; h < H1; ++h) {
        float e = lrelu(al_src[s * H1 + h] + al_dst[d * H1 + h]);
        atomicAdd(&den1[d * H1 + h], __expf(e - dec_f(m1[d * H1 + h])));
    }
}

// ---- edge msg pass: out1[dst] += alpha * h1[src] (2 edges per 256-thr block) ----
__global__ __launch_bounds__(256) void edge_msg1(
    const int* __restrict__ ei, const float* __restrict__ al_src,
    const float* __restrict__ al_dst, const unsigned* __restrict__ m1,
    const float* __restrict__ den1, const float* __restrict__ h1,
    float* __restrict__ out1)
{
    int t = threadIdx.x;
    int i = blockIdx.x * 2 + (t >> 7);
    int lane = t & 127;
    int s, d;
    if (i < N_EDGES) { s = ei[i]; d = ei[N_EDGES + i]; } else { s = d = i - N_EDGES; }
    int h = lane >> 5;
    float e = lrelu(al_src[s * H1 + h] + al_dst[d * H1 + h]);
    float alpha = __expf(e - dec_f(m1[d * H1 + h])) / den1[d * H1 + h];
    atomicAdd(&out1[(size_t)d * F_MID + lane], alpha * h1[(size_t)s * F_MID + lane]);
}

// ---- bias + ELU on layer-1 output (in place) ----
__global__ __launch_bounds__(256) void elu1(
    float* __restrict__ out1, const float* __restrict__ b1)
{
    size_t idx = (size_t)blockIdx.x * 256 + threadIdx.x;
    int j = idx & (F_MID - 1);
    out1[idx] = elu(out1[idx] + b1[j]);
}

// ---- layer 2 GEMM: h2 = x2 @ W2  (N x 128 @ 128 x 32), 2 nodes per 64-thr block ----
__global__ __launch_bounds__(64) void gemm2(
    const float* __restrict__ x2, const float* __restrict__ W2,
    const float* __restrict__ a_src2, const float* __restrict__ a_dst2,
    float* __restrict__ h2, float* __restrict__ al_src, float* __restrict__ al_dst)
{
    __shared__ float xs[2 * F_MID];
    __shared__ float hs[2 * C2];
    int t = threadIdx.x;
    int n0 = blockIdx.x * 2;
#pragma unroll
    for (int r = 0; r < 4; ++r) xs[t + 64 * r] = x2[(size_t)n0 * F_MID + t + 64 * r];
    __syncthreads();
    int local = t >> 5;
    int j = t & 31;
    int n = n0 + local;
    float acc = 0.f;
#pragma unroll
    for (int k = 0; k < F_MID; ++k) acc += xs[local * F_MID + k] * W2[k * C2 + j];
    h2[(size_t)n * C2 + j] = acc;
    hs[local * C2 + j] = acc;
    __syncthreads();
    if (j < 2) {
        const float* a = (j == 0) ? a_src2 : a_dst2;
        float s = 0.f;
#pragma unroll
        for (int c = 0; c < C2; ++c) s += hs[local * C2 + c] * a[c];
        if (j == 0) al_src[n] = s; else al_dst[n] = s;
    }
}

// ---- layer 2 edge passes (H=1) ----
__global__ __launch_bounds__(256) void edge_max2(
    const int* __restrict__ ei, const float* __restrict__ al_src,
    const float* __restrict__ al_dst, unsigned* __restrict__ m2)
{
    int i = blockIdx.x * 256 + threadIdx.x;
    if (i >= E_TOT) return;
    int s, d;
    if (i < N_EDGES) { s = ei[i]; d = ei[N_EDGES + i]; } else { s = d = i - N_EDGES; }
    float e = lrelu(al_src[s] + al_dst[d]);
    atomicMax(&m2[d], enc_f(e));
}

__global__ __launch_bounds__(256) void edge_den2(
    const int* __restrict__ ei, const float* __restrict__ al_src,
    const float* __restrict__ al_dst, const unsigned* __restrict__ m2,
    float* __restrict__ den2)
{
    int i = blockIdx.x * 256 + threadIdx.x;
    if (i >= E_TOT) return;
    int s, d;
    if (i < N_EDGES) { s = ei[i]; d = ei[N_EDGES + i]; } else { s = d = i - N_EDGES; }
    float e = lrelu(al_src[s] + al_dst[d]);
    atomicAdd(&den2[d], __expf(e - dec_f(m2[d])));
}

__global__ __launch_bounds__(256) void edge_msg2(
    const int* __restrict__ ei, const float* __restrict__ al_src,
    const float* __restrict__ al_dst, const unsigned* __restrict__ m2,
    const float* __restrict__ den2, const float* __restrict__ h2,
    float* __restrict__ out2)
{
    int t = threadIdx.x;
    int i = blockIdx.x * 8 + (t >> 5);
    int c = t & 31;
    int s, d;
    if (i < N_EDGES) { s = ei[i]; d = ei[N_EDGES + i]; } else { s = d = i - N_EDGES; }
    float e = lrelu(al_src[s] + al_dst[d]);
    float alpha = __expf(e - dec_f(m2[d])) / den2[d];
    atomicAdd(&out2[(size_t)d * C2 + c], alpha * h2[(size_t)s * C2 + c]);
}

// ---- bias + ELU + global mean-pool accumulation ----
__global__ __launch_bounds__(256) void final_pool(
    const float* __restrict__ out2, const float* __restrict__ b2,
    const int* __restrict__ batch, float* __restrict__ pooled, float* __restrict__ cnt)
{
    size_t idx = (size_t)blockIdx.x * 256 + threadIdx.x;
    int n = (int)(idx >> 5);
    int c = (int)(idx & 31);
    float v = elu(out2[idx] + b2[c]);
    int g = batch[n];
    atomicAdd(&pooled[g * C2 + c], v);
    if (c == 0) atomicAdd(&cnt[g], 1.0f);
}

// ---- classifier head: one thread per graph ----
__global__ __launch_bounds__(256) void head_k(
    const float* __restrict__ pooled, const float* __restrict__ cnt,
    const float* __restrict__ clinical,
    const float* __restrict__ Wc1, const float* __restrict__ bc1,
    const float* __restrict__ Wc2, const float* __restrict__ bc2,
    float* __restrict__ out)
{
    int g = threadIdx.x;
    float fused[C2 + CLIN];
    float inv = 1.f / cnt[g];
#pragma unroll
    for (int c = 0; c < C2; ++c) fused[c] = pooled[g * C2 + c] * inv;
#pragma unroll
    for (int c = 0; c < CLIN; ++c) fused[C2 + c] = clinical[g * CLIN + c];
    float o = bc2[0];
#pragma unroll
    for (int j = 0; j < 16; ++j) {
        float acc = bc1[j];
#pragma unroll
        for (int k = 0; k < C2 + CLIN; ++k) acc += fused[k] * Wc1[k * 16 + j];
        o += (acc > 0.f ? acc : expm1f(acc)) * Wc2[j];
    }
    out[g] = o;
}

extern "C" void kernel_launch(void* const* d_in, const int* in_sizes, int n_in,
                              void* d_out, int out_size, void* d_ws, size_t ws_size,
                              hipStream_t stream) {
    const float* x        = (const float*)d_in[0];
    const int*   ei       = (const int*)  d_in[1];
    const int*   batch    = (const int*)  d_in[2];
    const float* clinical = (const float*)d_in[3];
    const float* W1       = (const float*)d_in[4];
    const float* a_src1   = (const float*)d_in[5];
    const float* a_dst1   = (const float*)d_in[6];
    const float* b1       = (const float*)d_in[7];
    const float* W2       = (const float*)d_in[8];
    const float* a_src2   = (const float*)d_in[9];
    const float* a_dst2   = (const float*)d_in[10];
    const float* b2       = (const float*)d_in[11];
    const float* Wc1      = (const float*)d_in[12];
    const float* bc1      = (const float*)d_in[13];
    const float* Wc2      = (const float*)d_in[14];
    const float* bc2      = (const float*)d_in[15];
    float* out = (float*)d_out;

    const size_t N = N_NODES;
    float* ws = (float*)d_ws;
    size_t off = 0;
    float*    bufA    = ws + off; off += N * F_MID;      // h1; later h2 / out2
    float*    bufB    = ws + off; off += N * F_MID;      // out1 / x2
    float*    al_src1 = ws + off; off += N * H1;
    float*    al_dst1 = ws + off; off += N * H1;
    float*    al_s2   = ws + off; off += N;
    float*    al_d2   = ws + off; off += N;
    size_t zero_off = off;
    unsigned* m1      = (unsigned*)(ws + off); off += N * H1;
    float*    den1    = ws + off; off += N * H1;
    unsigned* m2      = (unsigned*)(ws + off); off += N;
    float*    den2    = ws + off; off += N;
    float*    pooled  = ws + off; off += (size_t)G_GRAPHS * C2;
    float*    cnt     = ws + off; off += G_GRAPHS;
    size_t zero_len = off - zero_off;

    float* h1   = bufA;
    float* out1 = bufB;                 // also x2 after elu1
    float* h2   = bufA;                 // h1 dead after edge_msg1
    float* out2 = bufA + N * C2;

    // zero accumulators (graph-capture-safe, stream-ordered)
    hipMemsetAsync(out1, 0, N * F_MID * sizeof(float), stream);
    hipMemsetAsync(ws + zero_off, 0, zero_len * sizeof(float), stream);

    gemm1<<<N_NODES, 128, 0, stream>>>(x, W1, a_src1, a_dst1, h1, al_src1, al_dst1);
    edge_max1<<<E_TOT / 256, 256, 0, stream>>>(ei, al_src1, al_dst1, m1);
    edge_den1<<<E_TOT / 256, 256, 0, stream>>>(ei, al_src1, al_dst1, m1, den1);
    edge_msg1<<<E_TOT / 2, 256, 0, stream>>>(ei, al_src1, al_dst1, m1, den1, h1, out1);
    elu1<<<(N_NODES * F_MID) / 256, 256, 0, stream>>>(out1, b1);

    hipMemsetAsync(out2, 0, N * C2 * sizeof(float), stream);  // after h1 consumed

    gemm2<<<N_NODES / 2, 64, 0, stream>>>(out1, W2, a_src2, a_dst2, h2, al_s2, al_d2);
    edge_max2<<<E_TOT / 256, 256, 0, stream>>>(ei, al_s2, al_d2, m2);
    edge_den2<<<E_TOT / 256, 256, 0, stream>>>(ei, al_s2, al_d2, m2, den2);
    edge_msg2<<<E_TOT / 8, 256, 0, stream>>>(ei, al_s2, al_d2, m2, den2, h2, out2);
    final_pool<<<(N_NODES * C2) / 256, 256, 0, stream>>>(out2, b2, batch, pooled, cnt);
    head_k<<<1, G_GRAPHS, 0, stream>>>(pooled, cnt, clinical, Wc1, bc1, Wc2, bc2, out);
}

// Round 2
// 1809.752 us; speedup vs baseline: 1.3058x; 1.3058x over previous
//
#include <hip/hip_runtime.h>
#include <math.h>

#define N_NODES 102400
#define N_EDGES 1638400
#define E_TOT   (N_EDGES + N_NODES)   // 1740800
#define G_GRAPHS 256
#define F_IN  64
#define H1    4
#define C1    32
#define F_MID 128                      // H1*C1
#define C2    32
#define CLIN  5
#define NEG   0.2f

__device__ __forceinline__ float lrelu(float x) { return x > 0.f ? x : NEG * x; }
__device__ __forceinline__ float elu(float x)   { return x > 0.f ? x : expm1f(x); }

// ---- layer 1 GEMM: h1 = x @ W1  (N x 64 @ 64 x 128), plus attention logits ----
__global__ __launch_bounds__(128) void gemm1(
    const float* __restrict__ x, const float* __restrict__ W1,
    const float* __restrict__ a_src, const float* __restrict__ a_dst,
    float* __restrict__ h1, float* __restrict__ al_src, float* __restrict__ al_dst)
{
    int n = blockIdx.x;
    int t = threadIdx.x;               // 0..127
    __shared__ float xs[F_IN];
    __shared__ float hs[F_MID];
    if (t < F_IN) xs[t] = x[(size_t)n * F_IN + t];
    __syncthreads();
    float acc = 0.f;
#pragma unroll
    for (int k = 0; k < F_IN; ++k) acc += xs[k] * W1[k * F_MID + t];
    h1[(size_t)n * F_MID + t] = acc;
    hs[t] = acc;
    __syncthreads();
    if (t < 8) {
        int h = t & 3;
        const float* a = (t < 4) ? a_src : a_dst;
        float s = 0.f;
#pragma unroll
        for (int c = 0; c < C1; ++c) s += hs[h * C1 + c] * a[h * C1 + c];
        if (t < 4) al_src[n * H1 + h] = s;
        else       al_dst[n * H1 + h] = s;
    }
}

// ---- fused layer-1 edge pass: out1[dst] += exp(e)*h1[src], den1[dst] += exp(e) ----
__global__ __launch_bounds__(256) void edge_acc1(
    const int* __restrict__ ei, const float* __restrict__ al_src,
    const float* __restrict__ al_dst, const float* __restrict__ h1,
    float* __restrict__ out1, float* __restrict__ den1)
{
    int t = threadIdx.x;
    int i = blockIdx.x * 2 + (t >> 7);
    int lane = t & 127;
    int s, d;
    if (i < N_EDGES) { s = ei[i]; d = ei[N_EDGES + i]; } else { s = d = i - N_EDGES; }
    int h = lane >> 5;
    float w = __expf(lrelu(al_src[s * H1 + h] + al_dst[d * H1 + h]));
    atomicAdd(&out1[(size_t)d * F_MID + lane], w * h1[(size_t)s * F_MID + lane]);
    if ((lane & 31) == 0) atomicAdd(&den1[d * H1 + h], w);
}

// ---- normalize + bias + ELU on layer-1 output (in place) ----
__global__ __launch_bounds__(256) void elu1(
    float* __restrict__ out1, const float* __restrict__ den1, const float* __restrict__ b1)
{
    size_t idx = (size_t)blockIdx.x * 256 + threadIdx.x;
    int j = idx & (F_MID - 1);
    int n = (int)(idx >> 7);
    float v = out1[idx] / den1[n * H1 + (j >> 5)];
    out1[idx] = elu(v + b1[j]);
}

// ---- layer 2 GEMM: h2 = x2 @ W2  (N x 128 @ 128 x 32), 2 nodes per 64-thr block ----
__global__ __launch_bounds__(64) void gemm2(
    const float* __restrict__ x2, const float* __restrict__ W2,
    const float* __restrict__ a_src2, const float* __restrict__ a_dst2,
    float* __restrict__ h2, float* __restrict__ al_src, float* __restrict__ al_dst)
{
    __shared__ float xs[2 * F_MID];
    __shared__ float hs[2 * C2];
    int t = threadIdx.x;
    int n0 = blockIdx.x * 2;
#pragma unroll
    for (int r = 0; r < 4; ++r) xs[t + 64 * r] = x2[(size_t)n0 * F_MID + t + 64 * r];
    __syncthreads();
    int local = t >> 5;
    int j = t & 31;
    int n = n0 + local;
    float acc = 0.f;
#pragma unroll
    for (int k = 0; k < F_MID; ++k) acc += xs[local * F_MID + k] * W2[k * C2 + j];
    h2[(size_t)n * C2 + j] = acc;
    hs[local * C2 + j] = acc;
    __syncthreads();
    if (j < 2) {
        const float* a = (j == 0) ? a_src2 : a_dst2;
        float s = 0.f;
#pragma unroll
        for (int c = 0; c < C2; ++c) s += hs[local * C2 + c] * a[c];
        if (j == 0) al_src[n] = s; else al_dst[n] = s;
    }
}

// ---- fused layer-2 edge pass (H=1) ----
__global__ __launch_bounds__(256) void edge_acc2(
    const int* __restrict__ ei, const float* __restrict__ al_src,
    const float* __restrict__ al_dst, const float* __restrict__ h2,
    float* __restrict__ out2, float* __restrict__ den2)
{
    int t = threadIdx.x;
    int i = blockIdx.x * 8 + (t >> 5);
    int c = t & 31;
    int s, d;
    if (i < N_EDGES) { s = ei[i]; d = ei[N_EDGES + i]; } else { s = d = i - N_EDGES; }
    float w = __expf(lrelu(al_src[s] + al_dst[d]));
    atomicAdd(&out2[(size_t)d * C2 + c], w * h2[(size_t)s * C2 + c]);
    if (c == 0) atomicAdd(&den2[d], w);
}

// ---- normalize + bias + ELU + global mean-pool accumulation ----
__global__ __launch_bounds__(256) void final_pool(
    const float* __restrict__ out2, const float* __restrict__ den2,
    const float* __restrict__ b2, const int* __restrict__ batch,
    float* __restrict__ pooled, float* __restrict__ cnt)
{
    size_t idx = (size_t)blockIdx.x * 256 + threadIdx.x;
    int n = (int)(idx >> 5);
    int c = (int)(idx & 31);
    float v = elu(out2[idx] / den2[n] + b2[c]);
    int g = batch[n];
    atomicAdd(&pooled[g * C2 + c], v);
    if (c == 0) atomicAdd(&cnt[g], 1.0f);
}

// ---- classifier head: one thread per graph ----
__global__ __launch_bounds__(256) void head_k(
    const float* __restrict__ pooled, const float* __restrict__ cnt,
    const float* __restrict__ clinical,
    const float* __restrict__ Wc1, const float* __restrict__ bc1,
    const float* __restrict__ Wc2, const float* __restrict__ bc2,
    float* __restrict__ out)
{
    int g = threadIdx.x;
    float fused[C2 + CLIN];
    float inv = 1.f / cnt[g];
#pragma unroll
    for (int c = 0; c < C2; ++c) fused[c] = pooled[g * C2 + c] * inv;
#pragma unroll
    for (int c = 0; c < CLIN; ++c) fused[C2 + c] = clinical[g * CLIN + c];
    float o = bc2[0];
#pragma unroll
    for (int j = 0; j < 16; ++j) {
        float acc = bc1[j];
#pragma unroll
        for (int k = 0; k < C2 + CLIN; ++k) acc += fused[k] * Wc1[k * 16 + j];
        o += (acc > 0.f ? acc : expm1f(acc)) * Wc2[j];
    }
    out[g] = o;
}

extern "C" void kernel_launch(void* const* d_in, const int* in_sizes, int n_in,
                              void* d_out, int out_size, void* d_ws, size_t ws_size,
                              hipStream_t stream) {
    const float* x        = (const float*)d_in[0];
    const int*   ei       = (const int*)  d_in[1];
    const int*   batch    = (const int*)  d_in[2];
    const float* clinical = (const float*)d_in[3];
    const float* W1       = (const float*)d_in[4];
    const float* a_src1   = (const float*)d_in[5];
    const float* a_dst1   = (const float*)d_in[6];
    const float* b1       = (const float*)d_in[7];
    const float* W2       = (const float*)d_in[8];
    const float* a_src2   = (const float*)d_in[9];
    const float* a_dst2   = (const float*)d_in[10];
    const float* b2       = (const float*)d_in[11];
    const float* Wc1      = (const float*)d_in[12];
    const float* bc1      = (const float*)d_in[13];
    const float* Wc2      = (const float*)d_in[14];
    const float* bc2      = (const float*)d_in[15];
    float* out = (float*)d_out;

    const size_t N = N_NODES;
    float* ws = (float*)d_ws;
    size_t off = 0;
    float*    bufA    = ws + off; off += N * F_MID;      // h1; later h2 / out2
    float*    bufB    = ws + off; off += N * F_MID;      // out1 / x2
    float*    al_src1 = ws + off; off += N * H1;
    float*    al_dst1 = ws + off; off += N * H1;
    float*    al_s2   = ws + off; off += N;
    float*    al_d2   = ws + off; off += N;
    size_t zero_off = off;
    float*    den1    = ws + off; off += N * H1;
    float*    den2    = ws + off; off += N;
    float*    pooled  = ws + off; off += (size_t)G_GRAPHS * C2;
    float*    cnt     = ws + off; off += G_GRAPHS;
    size_t zero_len = off - zero_off;

    float* h1   = bufA;
    float* out1 = bufB;                 // also x2 after elu1
    float* h2   = bufA;                 // h1 dead after edge_acc1
    float* out2 = bufA + N * C2;

    // zero accumulators (graph-capture-safe, stream-ordered)
    hipMemsetAsync(out1, 0, N * F_MID * sizeof(float), stream);
    hipMemsetAsync(ws + zero_off, 0, zero_len * sizeof(float), stream);

    gemm1<<<N_NODES, 128, 0, stream>>>(x, W1, a_src1, a_dst1, h1, al_src1, al_dst1);
    edge_acc1<<<E_TOT / 2, 256, 0, stream>>>(ei, al_src1, al_dst1, h1, out1, den1);
    elu1<<<(N_NODES * F_MID) / 256, 256, 0, stream>>>(out1, den1, b1);

    hipMemsetAsync(out2, 0, N * C2 * sizeof(float), stream);  // after h1 consumed

    gemm2<<<N_NODES / 2, 64, 0, stream>>>(out1, W2, a_src2, a_dst2, h2, al_s2, al_d2);
    edge_acc2<<<E_TOT / 8, 256, 0, stream>>>(ei, al_s2, al_d2, h2, out2, den2);
    final_pool<<<(N_NODES * C2) / 256, 256, 0, stream>>>(out2, den2, b2, batch, pooled, cnt);
    head_k<<<1, G_GRAPHS, 0, stream>>>(pooled, cnt, clinical, Wc1, bc1, Wc2, bc2, out);
}

// Round 3
// 1125.372 us; speedup vs baseline: 2.1000x; 1.6081x over previous
//
#include <hip/hip_runtime.h>
#include <math.h>

#define N_NODES 102400
#define N_EDGES 1638400
#define E_TOT   (N_EDGES + N_NODES)
#define G_GRAPHS 256
#define F_IN  64
#define H1    4
#define C1    32
#define F_MID 128
#define C2    32
#define CLIN  5
#define NEG   0.2f

__device__ __forceinline__ float lrelu(float x) { return x > 0.f ? x : NEG * x; }
__device__ __forceinline__ float elu(float x)   { return x > 0.f ? x : expm1f(x); }

// ---- layer 1 GEMM: h1 = x @ W1  (N x 64 @ 64 x 128), plus attention logits ----
__global__ __launch_bounds__(128) void gemm1(
    const float* __restrict__ x, const float* __restrict__ W1,
    const float* __restrict__ a_src, const float* __restrict__ a_dst,
    float* __restrict__ h1, float* __restrict__ al_src, float* __restrict__ al_dst)
{
    int n = blockIdx.x;
    int t = threadIdx.x;
    __shared__ float xs[F_IN];
    __shared__ float hs[F_MID];
    if (t < F_IN) xs[t] = x[(size_t)n * F_IN + t];
    __syncthreads();
    float acc = 0.f;
#pragma unroll
    for (int k = 0; k < F_IN; ++k) acc += xs[k] * W1[k * F_MID + t];
    h1[(size_t)n * F_MID + t] = acc;
    hs[t] = acc;
    __syncthreads();
    if (t < 8) {
        int h = t & 3;
        const float* a = (t < 4) ? a_src : a_dst;
        float s = 0.f;
#pragma unroll
        for (int c = 0; c < C1; ++c) s += hs[h * C1 + c] * a[h * C1 + c];
        if (t < 4) al_src[n * H1 + h] = s;
        else       al_dst[n * H1 + h] = s;
    }
}

// ---------------- CSR build ----------------
__global__ __launch_bounds__(256) void hist_k(const int* __restrict__ ei, int* __restrict__ deg) {
    int i = blockIdx.x * 256 + threadIdx.x;
    if (i < N_EDGES) atomicAdd(&deg[ei[N_EDGES + i]], 1);
}

__global__ __launch_bounds__(256) void scanA(const int* __restrict__ deg,
                                             int* __restrict__ excl, int* __restrict__ bsum) {
    __shared__ int s[256];
    int t = threadIdx.x;
    int n = blockIdx.x * 256 + t;
    int v = deg[n];
    s[t] = v;
    __syncthreads();
    for (int off = 1; off < 256; off <<= 1) {
        int tmp = (t >= off) ? s[t - off] : 0;
        __syncthreads();
        s[t] += tmp;
        __syncthreads();
    }
    excl[n] = s[t] - v;
    if (t == 255) bsum[blockIdx.x] = s[255];
}

__global__ __launch_bounds__(512) void scanB(const int* __restrict__ bsum, int* __restrict__ boff) {
    __shared__ int s[512];
    int t = threadIdx.x;
    int v = (t < 400) ? bsum[t] : 0;
    s[t] = v;
    __syncthreads();
    for (int off = 1; off < 512; off <<= 1) {
        int tmp = (t >= off) ? s[t - off] : 0;
        __syncthreads();
        s[t] += tmp;
        __syncthreads();
    }
    if (t < 400) boff[t] = s[t] - v;
}

// row_ptr[n] = excl[n] + boff[blk]  (in place on excl), and init cursor
__global__ __launch_bounds__(256) void scanC(int* __restrict__ row_ptr, const int* __restrict__ boff,
                                             int* __restrict__ cursor) {
    int n = blockIdx.x * 256 + threadIdx.x;
    int v = row_ptr[n] + boff[blockIdx.x];
    row_ptr[n] = v;
    cursor[n] = v;
}

__global__ __launch_bounds__(256) void scatter_k(const int* __restrict__ ei,
                                                 int* __restrict__ cursor, int* __restrict__ col) {
    int i = blockIdx.x * 256 + threadIdx.x;
    if (i < N_EDGES) {
        int d = ei[N_EDGES + i];
        int pos = atomicAdd(&cursor[d], 1);
        col[pos] = ei[i];
    }
}

// ---- layer-1 dst-centric gather: out1[d] = elu( (sum_e w*h1[s]) / (sum_e w) + b1 ) ----
// one block (128 thr) per dst; lane = channel; head = lane>>5. Self-loop analytic.
// after scatter_k, cursor[d] == row end.
__global__ __launch_bounds__(128) void gather1(
    const int* __restrict__ row_ptr, const int* __restrict__ row_end,
    const int* __restrict__ col, const float* __restrict__ al_src,
    const float* __restrict__ al_dst, const float* __restrict__ h1,
    const float* __restrict__ b1, float* __restrict__ out1)
{
    int d = blockIdx.x;
    int lane = threadIdx.x;
    int h = lane >> 5;
    float ad = al_dst[d * H1 + h];
    float w = __expf(lrelu(al_src[d * H1 + h] + ad));
    float acc = w * h1[(size_t)d * F_MID + lane];
    float den = w;
    int e0 = row_ptr[d], e1 = row_end[d];
    for (int e = e0; e < e1; ++e) {
        int s = col[e];
        float we = __expf(lrelu(al_src[s * H1 + h] + ad));
        acc += we * h1[(size_t)s * F_MID + lane];
        den += we;
    }
    out1[(size_t)d * F_MID + lane] = elu(acc / den + b1[lane]);
}

// ---- layer 2 GEMM: h2 = x2 @ W2  (N x 128 @ 128 x 32), 2 nodes per 64-thr block ----
__global__ __launch_bounds__(64) void gemm2(
    const float* __restrict__ x2, const float* __restrict__ W2,
    const float* __restrict__ a_src2, const float* __restrict__ a_dst2,
    float* __restrict__ h2, float* __restrict__ al_src, float* __restrict__ al_dst)
{
    __shared__ float xs[2 * F_MID];
    __shared__ float hs[2 * C2];
    int t = threadIdx.x;
    int n0 = blockIdx.x * 2;
#pragma unroll
    for (int r = 0; r < 4; ++r) xs[t + 64 * r] = x2[(size_t)n0 * F_MID + t + 64 * r];
    __syncthreads();
    int local = t >> 5;
    int j = t & 31;
    int n = n0 + local;
    float acc = 0.f;
#pragma unroll
    for (int k = 0; k < F_MID; ++k) acc += xs[local * F_MID + k] * W2[k * C2 + j];
    h2[(size_t)n * C2 + j] = acc;
    hs[local * C2 + j] = acc;
    __syncthreads();
    if (j < 2) {
        const float* a = (j == 0) ? a_src2 : a_dst2;
        float s = 0.f;
#pragma unroll
        for (int c = 0; c < C2; ++c) s += hs[local * C2 + c] * a[c];
        if (j == 0) al_src[n] = s; else al_dst[n] = s;
    }
}

// ---- layer-2 gather + normalize + ELU + mean-pool accumulate (out2 never stored) ----
// 8 dsts per 256-thr block; 32 threads per dst.
__global__ __launch_bounds__(256) void gather2(
    const int* __restrict__ row_ptr, const int* __restrict__ row_end,
    const int* __restrict__ col, const float* __restrict__ al_src,
    const float* __restrict__ al_dst, const float* __restrict__ h2,
    const float* __restrict__ b2, const int* __restrict__ batch,
    float* __restrict__ pooled, float* __restrict__ cnt)
{
    int t = threadIdx.x;
    int d = blockIdx.x * 8 + (t >> 5);
    int c = t & 31;
    float ad = al_dst[d];
    float w = __expf(lrelu(al_src[d] + ad));
    float acc = w * h2[(size_t)d * C2 + c];
    float den = w;
    int e0 = row_ptr[d], e1 = row_end[d];
    for (int e = e0; e < e1; ++e) {
        int s = col[e];
        float we = __expf(lrelu(al_src[s] + ad));
        acc += we * h2[(size_t)s * C2 + c];
        den += we;
    }
    float v = elu(acc / den + b2[c]);
    int g = batch[d];
    atomicAdd(&pooled[g * C2 + c], v);
    if (c == 0) atomicAdd(&cnt[g], 1.0f);
}

// ---- classifier head: one thread per graph ----
__global__ __launch_bounds__(256) void head_k(
    const float* __restrict__ pooled, const float* __restrict__ cnt,
    const float* __restrict__ clinical,
    const float* __restrict__ Wc1, const float* __restrict__ bc1,
    const float* __restrict__ Wc2, const float* __restrict__ bc2,
    float* __restrict__ out)
{
    int g = threadIdx.x;
    float fused[C2 + CLIN];
    float inv = 1.f / cnt[g];
#pragma unroll
    for (int c = 0; c < C2; ++c) fused[c] = pooled[g * C2 + c] * inv;
#pragma unroll
    for (int c = 0; c < CLIN; ++c) fused[C2 + c] = clinical[g * CLIN + c];
    float o = bc2[0];
#pragma unroll
    for (int j = 0; j < 16; ++j) {
        float acc = bc1[j];
#pragma unroll
        for (int k = 0; k < C2 + CLIN; ++k) acc += fused[k] * Wc1[k * 16 + j];
        o += (acc > 0.f ? acc : expm1f(acc)) * Wc2[j];
    }
    out[g] = o;
}

extern "C" void kernel_launch(void* const* d_in, const int* in_sizes, int n_in,
                              void* d_out, int out_size, void* d_ws, size_t ws_size,
                              hipStream_t stream) {
    const float* x        = (const float*)d_in[0];
    const int*   ei       = (const int*)  d_in[1];
    const int*   batch    = (const int*)  d_in[2];
    const float* clinical = (const float*)d_in[3];
    const float* W1       = (const float*)d_in[4];
    const float* a_src1   = (const float*)d_in[5];
    const float* a_dst1   = (const float*)d_in[6];
    const float* b1       = (const float*)d_in[7];
    const float* W2       = (const float*)d_in[8];
    const float* a_src2   = (const float*)d_in[9];
    const float* a_dst2   = (const float*)d_in[10];
    const float* b2       = (const float*)d_in[11];
    const float* Wc1      = (const float*)d_in[12];
    const float* bc1      = (const float*)d_in[13];
    const float* Wc2      = (const float*)d_in[14];
    const float* bc2      = (const float*)d_in[15];
    float* out = (float*)d_out;

    const size_t N = N_NODES;
    float* ws = (float*)d_ws;
    size_t off = 0;
    float* bufA    = ws + off; off += N * F_MID;      // h1; later h2 (first N*C2)
    float* bufB    = ws + off; off += N * F_MID;      // out1 / x2
    float* al_src1 = ws + off; off += N * H1;
    float* al_dst1 = ws + off; off += N * H1;
    float* al_s2   = ws + off; off += N;
    float* al_d2   = ws + off; off += N;
    float* pooled  = ws + off; off += (size_t)G_GRAPHS * C2;
    float* cnt     = ws + off; off += G_GRAPHS;
    int* deg     = (int*)(ws + off); off += N;
    int* row_ptr = (int*)(ws + off); off += N;        // excl-scan, then row starts
    int* cursor  = (int*)(ws + off); off += N;        // after scatter: row ends
    int* bsum    = (int*)(ws + off); off += 512;
    int* boff    = (int*)(ws + off); off += 512;
    int* col     = (int*)(ws + off); off += N_EDGES;

    float* h1   = bufA;
    float* out1 = bufB;
    float* h2   = bufA;                               // h1 dead after gather1

    // zero accumulators (stream-ordered, graph-capture-safe)
    hipMemsetAsync(deg, 0, N * sizeof(int), stream);
    hipMemsetAsync(pooled, 0, (G_GRAPHS * C2 + G_GRAPHS) * sizeof(float), stream);

    // CSR build
    hist_k  <<<(N_EDGES + 255) / 256, 256, 0, stream>>>(ei, deg);
    scanA   <<<N_NODES / 256, 256, 0, stream>>>(deg, row_ptr, bsum);
    scanB   <<<1, 512, 0, stream>>>(bsum, boff);
    scanC   <<<N_NODES / 256, 256, 0, stream>>>(row_ptr, boff, cursor);
    scatter_k<<<(N_EDGES + 255) / 256, 256, 0, stream>>>(ei, cursor, col);

    // layer 1
    gemm1  <<<N_NODES, 128, 0, stream>>>(x, W1, a_src1, a_dst1, h1, al_src1, al_dst1);
    gather1<<<N_NODES, 128, 0, stream>>>(row_ptr, cursor, col, al_src1, al_dst1, h1, b1, out1);

    // layer 2
    gemm2  <<<N_NODES / 2, 64, 0, stream>>>(out1, W2, a_src2, a_dst2, h2, al_s2, al_d2);
    gather2<<<N_NODES / 8, 256, 0, stream>>>(row_ptr, cursor, col, al_s2, al_d2, h2, b2,
                                             batch, pooled, cnt);

    // head
    head_k<<<1, G_GRAPHS, 0, stream>>>(pooled, cnt, clinical, Wc1, bc1, Wc2, bc2, out);
}

// Round 4
// 607.357 us; speedup vs baseline: 3.8910x; 1.8529x over previous
//
#include <hip/hip_runtime.h>
#include <math.h>

#define N_NODES 102400
#define N_EDGES 1638400
#define G_GRAPHS 256
#define F_IN  64
#define H1    4
#define C1    32
#define F_MID 128
#define C2    32
#define CLIN  5
#define NEG   0.2f

__device__ __forceinline__ float lrelu(float x) { return x > 0.f ? x : NEG * x; }
__device__ __forceinline__ float elu(float x)   { return x > 0.f ? x : expm1f(x); }

// ---- layer 1 GEMM: h1 = x @ W1  (N x 64 @ 64 x 128), plus attention logits ----
__global__ __launch_bounds__(128) void gemm1(
    const float* __restrict__ x, const float* __restrict__ W1,
    const float* __restrict__ a_src, const float* __restrict__ a_dst,
    float* __restrict__ h1, float* __restrict__ al_src, float* __restrict__ al_dst)
{
    int n = blockIdx.x;
    int t = threadIdx.x;
    __shared__ float xs[F_IN];
    __shared__ float hs[F_MID];
    if (t < F_IN) xs[t] = x[(size_t)n * F_IN + t];
    __syncthreads();
    float acc = 0.f;
#pragma unroll
    for (int k = 0; k < F_IN; ++k) acc += xs[k] * W1[k * F_MID + t];
    h1[(size_t)n * F_MID + t] = acc;
    hs[t] = acc;
    __syncthreads();
    if (t < 8) {
        int h = t & 3;
        const float* a = (t < 4) ? a_src : a_dst;
        float s = 0.f;
#pragma unroll
        for (int c = 0; c < C1; ++c) s += hs[h * C1 + c] * a[h * C1 + c];
        if (t < 4) al_src[n * H1 + h] = s;
        else       al_dst[n * H1 + h] = s;
    }
}

// ---------------- CSR build ----------------
__global__ __launch_bounds__(256) void hist_k(const int* __restrict__ ei, int* __restrict__ deg) {
    int i = blockIdx.x * 256 + threadIdx.x;
    if (i < N_EDGES) atomicAdd(&deg[ei[N_EDGES + i]], 1);
}

__global__ __launch_bounds__(256) void scanA(const int* __restrict__ deg,
                                             int* __restrict__ excl, int* __restrict__ bsum) {
    __shared__ int s[256];
    int t = threadIdx.x;
    int n = blockIdx.x * 256 + t;
    int v = deg[n];
    s[t] = v;
    __syncthreads();
    for (int off = 1; off < 256; off <<= 1) {
        int tmp = (t >= off) ? s[t - off] : 0;
        __syncthreads();
        s[t] += tmp;
        __syncthreads();
    }
    excl[n] = s[t] - v;
    if (t == 255) bsum[blockIdx.x] = s[255];
}

__global__ __launch_bounds__(512) void scanB(const int* __restrict__ bsum, int* __restrict__ boff) {
    __shared__ int s[512];
    int t = threadIdx.x;
    int v = (t < 400) ? bsum[t] : 0;
    s[t] = v;
    __syncthreads();
    for (int off = 1; off < 512; off <<= 1) {
        int tmp = (t >= off) ? s[t - off] : 0;
        __syncthreads();
        s[t] += tmp;
        __syncthreads();
    }
    if (t < 400) boff[t] = s[t] - v;
}

__global__ __launch_bounds__(256) void scanC(int* __restrict__ row_ptr, const int* __restrict__ boff,
                                             int* __restrict__ cursor) {
    int n = blockIdx.x * 256 + threadIdx.x;
    int v = row_ptr[n] + boff[blockIdx.x];
    row_ptr[n] = v;
    cursor[n] = v;
}

__global__ __launch_bounds__(256) void scatter_k(const int* __restrict__ ei,
                                                 int* __restrict__ cursor, int* __restrict__ col) {
    int i = blockIdx.x * 256 + threadIdx.x;
    if (i < N_EDGES) {
        int d = ei[N_EDGES + i];
        int pos = atomicAdd(&cursor[d], 1);
        col[pos] = ei[i];
    }
}

// ---- layer-1 gather (float4, unroll-4) fused with gemm2 + attention logits 2 ----
// 8 dsts per 256-thr block; 32 lanes/dst, each lane owns 4 channels (float4).
__global__ __launch_bounds__(256) void gather1(
    const int* __restrict__ row_ptr, const int* __restrict__ row_end,
    const int* __restrict__ col, const float* __restrict__ al_src,
    const float* __restrict__ al_dst, const float* __restrict__ h1,
    const float* __restrict__ b1, const float* __restrict__ W2,
    const float* __restrict__ a_src2, const float* __restrict__ a_dst2,
    float* __restrict__ h2, float* __restrict__ al_s2, float* __restrict__ al_d2)
{
    __shared__ float os[8][F_MID];
    __shared__ float hsh[8][C2];
    int t = threadIdx.x;
    int r = t >> 5;                 // dst slot
    int c = t & 31;                 // lane: channels [4c, 4c+4)
    int d = blockIdx.x * 8 + r;
    int h = c >> 3;                 // head of these 4 channels
    const float4* h1v = (const float4*)h1;
    float ad = al_dst[d * H1 + h];
    float w = __expf(lrelu(al_src[d * H1 + h] + ad));  // self loop
    float4 v = h1v[(size_t)d * 32 + c];
    float ax = w * v.x, ay = w * v.y, az = w * v.z, aw = w * v.w;
    float den = w;
    int e0 = row_ptr[d], e1 = row_end[d];
    int e = e0;
    for (; e + 4 <= e1; e += 4) {
        int s0 = col[e], s1 = col[e + 1], s2 = col[e + 2], s3 = col[e + 3];
        float4 v0 = h1v[(size_t)s0 * 32 + c];
        float4 v1 = h1v[(size_t)s1 * 32 + c];
        float4 v2 = h1v[(size_t)s2 * 32 + c];
        float4 v3 = h1v[(size_t)s3 * 32 + c];
        float w0 = __expf(lrelu(al_src[s0 * H1 + h] + ad));
        float w1 = __expf(lrelu(al_src[s1 * H1 + h] + ad));
        float w2 = __expf(lrelu(al_src[s2 * H1 + h] + ad));
        float w3 = __expf(lrelu(al_src[s3 * H1 + h] + ad));
        ax += w0 * v0.x + w1 * v1.x + w2 * v2.x + w3 * v3.x;
        ay += w0 * v0.y + w1 * v1.y + w2 * v2.y + w3 * v3.y;
        az += w0 * v0.z + w1 * v1.z + w2 * v2.z + w3 * v3.z;
        aw += w0 * v0.w + w1 * v1.w + w2 * v2.w + w3 * v3.w;
        den += w0 + w1 + w2 + w3;
    }
    for (; e < e1; ++e) {
        int s = col[e];
        float4 vs = h1v[(size_t)s * 32 + c];
        float we = __expf(lrelu(al_src[s * H1 + h] + ad));
        ax += we * vs.x; ay += we * vs.y; az += we * vs.z; aw += we * vs.w;
        den += we;
    }
    float inv = 1.f / den;
    const float4 bv = ((const float4*)b1)[c];
    os[r][4 * c + 0] = elu(ax * inv + bv.x);
    os[r][4 * c + 1] = elu(ay * inv + bv.y);
    os[r][4 * c + 2] = elu(az * inv + bv.z);
    os[r][4 * c + 3] = elu(aw * inv + bv.w);
    __syncthreads();
    // h2[d][c] = sum_k os[r][k] * W2[k][c]
    float p = 0.f;
#pragma unroll
    for (int k = 0; k < F_MID; ++k) p += os[r][k] * W2[k * C2 + c];
    h2[(size_t)d * C2 + c] = p;
    hsh[r][c] = p;
    __syncthreads();
    if (c < 2) {
        const float* a = c ? a_dst2 : a_src2;
        float sum = 0.f;
#pragma unroll
        for (int k = 0; k < C2; ++k) sum += hsh[r][k] * a[k];
        if (c) al_d2[d] = sum; else al_s2[d] = sum;
    }
}

// ---- layer-2 gather (float4, unroll-4) + normalize + ELU + pooled reduce ----
// 32 dsts per 256-thr block; 8 lanes/dst, each lane owns 4 channels.
__global__ __launch_bounds__(256) void gather2(
    const int* __restrict__ row_ptr, const int* __restrict__ row_end,
    const int* __restrict__ col, const float* __restrict__ al_src,
    const float* __restrict__ al_dst, const float* __restrict__ h2,
    const float* __restrict__ b2, const int* __restrict__ batch,
    float* __restrict__ pooled)
{
    __shared__ float sv[32][C2];
    int t = threadIdx.x;
    int r = t >> 3;                 // dst slot 0..31
    int c = t & 7;                  // float4 slot: channels [4c, 4c+4)
    int d = blockIdx.x * 32 + r;
    const float4* h2v = (const float4*)h2;
    float ad = al_dst[d];
    float w = __expf(lrelu(al_src[d] + ad));   // self loop
    float4 v = h2v[(size_t)d * 8 + c];
    float ax = w * v.x, ay = w * v.y, az = w * v.z, aw = w * v.w;
    float den = w;
    int e0 = row_ptr[d], e1 = row_end[d];
    int e = e0;
    for (; e + 4 <= e1; e += 4) {
        int s0 = col[e], s1 = col[e + 1], s2 = col[e + 2], s3 = col[e + 3];
        float4 v0 = h2v[(size_t)s0 * 8 + c];
        float4 v1 = h2v[(size_t)s1 * 8 + c];
        float4 v2 = h2v[(size_t)s2 * 8 + c];
        float4 v3 = h2v[(size_t)s3 * 8 + c];
        float w0 = __expf(lrelu(al_src[s0] + ad));
        float w1 = __expf(lrelu(al_src[s1] + ad));
        float w2 = __expf(lrelu(al_src[s2] + ad));
        float w3 = __expf(lrelu(al_src[s3] + ad));
        ax += w0 * v0.x + w1 * v1.x + w2 * v2.x + w3 * v3.x;
        ay += w0 * v0.y + w1 * v1.y + w2 * v2.y + w3 * v3.y;
        az += w0 * v0.z + w1 * v1.z + w2 * v2.z + w3 * v3.z;
        aw += w0 * v0.w + w1 * v1.w + w2 * v2.w + w3 * v3.w;
        den += w0 + w1 + w2 + w3;
    }
    for (; e < e1; ++e) {
        int s = col[e];
        float4 vs = h2v[(size_t)s * 8 + c];
        float we = __expf(lrelu(al_src[s] + ad));
        ax += we * vs.x; ay += we * vs.y; az += we * vs.z; aw += we * vs.w;
        den += we;
    }
    float inv = 1.f / den;
    const float4 bv = ((const float4*)b2)[c];
    sv[r][4 * c + 0] = elu(ax * inv + bv.x);
    sv[r][4 * c + 1] = elu(ay * inv + bv.y);
    sv[r][4 * c + 2] = elu(az * inv + bv.z);
    sv[r][4 * c + 3] = elu(aw * inv + bv.w);
    __syncthreads();
    // pool: the 32 consecutive dsts span at most 2 graphs (400 nodes/graph)
    int d0 = blockIdx.x * 32;
    int g0 = batch[d0], g1 = batch[d0 + 31];
    if (t < 64) {
        int which = t >> 5, ch = t & 31;
        int g = which ? g1 : g0;
        if (which == 0 || g1 != g0) {
            float s = 0.f;
            for (int rr = 0; rr < 32; ++rr)
                if (batch[d0 + rr] == g) s += sv[rr][ch];
            atomicAdd(&pooled[g * C2 + ch], s);
        }
    }
}

// ---- classifier head: one thread per graph (each graph has exactly 400 nodes) ----
__global__ __launch_bounds__(256) void head_k(
    const float* __restrict__ pooled, const float* __restrict__ clinical,
    const float* __restrict__ Wc1, const float* __restrict__ bc1,
    const float* __restrict__ Wc2, const float* __restrict__ bc2,
    float* __restrict__ out)
{
    int g = threadIdx.x;
    float fused[C2 + CLIN];
    const float inv = 1.f / 400.f;
#pragma unroll
    for (int c = 0; c < C2; ++c) fused[c] = pooled[g * C2 + c] * inv;
#pragma unroll
    for (int c = 0; c < CLIN; ++c) fused[C2 + c] = clinical[g * CLIN + c];
    float o = bc2[0];
#pragma unroll
    for (int j = 0; j < 16; ++j) {
        float acc = bc1[j];
#pragma unroll
        for (int k = 0; k < C2 + CLIN; ++k) acc += fused[k] * Wc1[k * 16 + j];
        o += (acc > 0.f ? acc : expm1f(acc)) * Wc2[j];
    }
    out[g] = o;
}

extern "C" void kernel_launch(void* const* d_in, const int* in_sizes, int n_in,
                              void* d_out, int out_size, void* d_ws, size_t ws_size,
                              hipStream_t stream) {
    const float* x        = (const float*)d_in[0];
    const int*   ei       = (const int*)  d_in[1];
    const int*   batch    = (const int*)  d_in[2];
    const float* clinical = (const float*)d_in[3];
    const float* W1       = (const float*)d_in[4];
    const float* a_src1   = (const float*)d_in[5];
    const float* a_dst1   = (const float*)d_in[6];
    const float* b1       = (const float*)d_in[7];
    const float* W2       = (const float*)d_in[8];
    const float* a_src2   = (const float*)d_in[9];
    const float* a_dst2   = (const float*)d_in[10];
    const float* b2       = (const float*)d_in[11];
    const float* Wc1      = (const float*)d_in[12];
    const float* bc1      = (const float*)d_in[13];
    const float* Wc2      = (const float*)d_in[14];
    const float* bc2      = (const float*)d_in[15];
    float* out = (float*)d_out;

    const size_t N = N_NODES;
    float* ws = (float*)d_ws;
    size_t off = 0;
    float* h1      = ws + off; off += N * F_MID;
    float* h2      = ws + off; off += N * C2;
    float* al_src1 = ws + off; off += N * H1;
    float* al_dst1 = ws + off; off += N * H1;
    float* al_s2   = ws + off; off += N;
    float* al_d2   = ws + off; off += N;
    float* pooled  = ws + off; off += (size_t)G_GRAPHS * C2;
    int* deg     = (int*)(ws + off); off += N;
    int* row_ptr = (int*)(ws + off); off += N;
    int* cursor  = (int*)(ws + off); off += N;        // after scatter: row ends
    int* bsum    = (int*)(ws + off); off += 512;
    int* boff    = (int*)(ws + off); off += 512;
    int* col     = (int*)(ws + off); off += N_EDGES;

    hipMemsetAsync(deg, 0, N * sizeof(int), stream);
    hipMemsetAsync(pooled, 0, G_GRAPHS * C2 * sizeof(float), stream);

    // CSR build
    hist_k   <<<(N_EDGES + 255) / 256, 256, 0, stream>>>(ei, deg);
    scanA    <<<N_NODES / 256, 256, 0, stream>>>(deg, row_ptr, bsum);
    scanB    <<<1, 512, 0, stream>>>(bsum, boff);
    scanC    <<<N_NODES / 256, 256, 0, stream>>>(row_ptr, boff, cursor);
    scatter_k<<<(N_EDGES + 255) / 256, 256, 0, stream>>>(ei, cursor, col);

    // layer 1 (+ fused layer-2 GEMM & logits)
    gemm1  <<<N_NODES, 128, 0, stream>>>(x, W1, a_src1, a_dst1, h1, al_src1, al_dst1);
    gather1<<<N_NODES / 8, 256, 0, stream>>>(row_ptr, cursor, col, al_src1, al_dst1, h1,
                                             b1, W2, a_src2, a_dst2, h2, al_s2, al_d2);

    // layer 2 gather (+ fused pooling)
    gather2<<<N_NODES / 32, 256, 0, stream>>>(row_ptr, cursor, col, al_s2, al_d2, h2,
                                              b2, batch, pooled);

    // head
    head_k<<<1, G_GRAPHS, 0, stream>>>(pooled, clinical, Wc1, bc1, Wc2, bc2, out);
}